// Round 6
// baseline (118.834 us; speedup 1.0000x reference)
//
#include <hip/hip_runtime.h>

// ForwardDistance: out[b,n,m] = sum_a agg[a] * tanh(datalin[b,n,a] + critlin[b,m,a])
// tanh(x+y) = 1 - 2/(1 + e^{2x} e^{2y});  e^{2(p1+p2+b)} = E1 * E2 (K-split factors)
// Phase 1 (proj_exp, unchanged from R5): LDS-tiled fp32 GEMM, 64x64 tile, K split in
//   two 256-halves across blocks (512 blocks = 2/CU). bf16 factor planes in ws.
// Phase 2 (tanh_reduce): R5 was LDS-ISSUE-BOUND (2x2 tile = 4 B LDS/term -> ~61k
//   LDS-cyc/CU ~ 25 us). Now 4x4 register tile (64x64 out tile) = 2 B/term, all
//   ds_read_b128; a split in halves across blocks (512 blocks, 2 waves/SIMD);
//   partial planes in ws, plain stores (no atomics). Pair-grouped rcp unchanged
//   (q <= 1+2^60, D = q0*q1 <= 2^120 < FLT_MAX).
// Phase 3 (combine): out = p0 + p1, float4, ~12 MB L2 traffic.

#define A_DIM 256
#define K_DIM 512
#define NROWS 2048   // rows per source (B*N == B*M)

typedef unsigned short ushort;
typedef __attribute__((ext_vector_type(4))) unsigned short us4;

__device__ inline ushort f2bf(float x) {    // round-to-nearest-even bf16
    union { float f; unsigned u; } v; v.f = x;
    unsigned r = v.u + 0x7FFFu + ((v.u >> 16) & 1u);
    return (ushort)(r >> 16);
}
__device__ inline float bf2f(ushort h) {
    union { unsigned u; float f; } v; v.u = ((unsigned)h) << 16; return v.f;
}

__global__ __launch_bounds__(256) void proj_exp_kernel(
    const float* __restrict__ data, const float* __restrict__ crit,
    const float* __restrict__ Wl, const float* __restrict__ bl,
    const float* __restrict__ Wr, const float* __restrict__ br,
    ushort* __restrict__ ws16)
{
    __shared__ __align__(16) float Xs[16][68];   // [k][row]
    __shared__ __align__(16) float Wsm[16][64];  // [k][col]

    const int t   = threadIdx.x;
    const int bid = blockIdx.x;
    const int ct  = bid & 3;            // col tile (64 cols)
    const int rt  = (bid >> 2) & 31;    // row tile (64 rows)
    const int kh  = (bid >> 7) & 1;     // K half
    const int src = bid >> 8;           // 0 = data, 1 = crit

    const int r0 = rt * 64, c0 = ct * 64, kb = kh * 256;
    const float* X    = src ? crit : data;
    const float* W    = src ? Wr   : Wl;
    const float* bias = src ? br   : bl;
    ushort* ET = ws16 + (size_t)(src * 2 + kh) * ((size_t)A_DIM * NROWS);

    const int tx = t & 15;              // 4 cols
    const int ty = t >> 4;              // 4 rows
    const int sr = t >> 2;              // X staging: row 0..63
    const int sk = (t & 3) * 4;         //            k seg
    const int wk = t >> 4;              // W staging: k row 0..15
    const int wc = (t & 15) * 4;        //            col seg

    float acc[4][4];
#pragma unroll
    for (int i = 0; i < 4; i++)
#pragma unroll
        for (int j = 0; j < 4; j++) acc[i][j] = 0.f;

    for (int k0 = 0; k0 < 256; k0 += 16) {
        float4 xv = *(const float4*)(X + (size_t)(r0 + sr) * K_DIM + kb + k0 + sk);
        float4 wv = *(const float4*)(W + (size_t)(kb + k0 + wk) * A_DIM + c0 + wc);
        __syncthreads();                // previous chunk's LDS reads complete
        Xs[sk + 0][sr] = xv.x; Xs[sk + 1][sr] = xv.y;
        Xs[sk + 2][sr] = xv.z; Xs[sk + 3][sr] = xv.w;
        *(float4*)&Wsm[wk][wc] = wv;
        __syncthreads();
#pragma unroll
        for (int kk = 0; kk < 16; kk++) {
            float4 a4 = *(const float4*)&Xs[kk][ty * 4];
            float4 b4 = *(const float4*)&Wsm[kk][tx * 4];
            const float aa[4] = {a4.x, a4.y, a4.z, a4.w};
            const float bb[4] = {b4.x, b4.y, b4.z, b4.w};
#pragma unroll
            for (int i = 0; i < 4; i++)
#pragma unroll
                for (int j = 0; j < 4; j++)
                    acc[i][j] = fmaf(aa[i], bb[j], acc[i][j]);
        }
    }

    // factor: E = exp2( clamp( 2*log2(e)*(acc [+bias if kh==0]), +-15 ) )
    const float c2 = 2.8853900817779268f;    // 2*log2(e)
    float bvv[4] = {0.f, 0.f, 0.f, 0.f};
    if (kh == 0) {
        float4 bv = *(const float4*)(bias + c0 + tx * 4);
        bvv[0] = bv.x; bvv[1] = bv.y; bvv[2] = bv.z; bvv[3] = bv.w;
    }
#pragma unroll
    for (int j = 0; j < 4; j++) {
        us4 ev;
#pragma unroll
        for (int i = 0; i < 4; i++) {
            float v = (acc[i][j] + bvv[j]) * c2;
            v = fminf(fmaxf(v, -15.f), 15.f);
            ev[i] = f2bf(__builtin_amdgcn_exp2f(v));
        }
        *(us4*)(ET + (size_t)(c0 + tx * 4 + j) * NROWS + r0 + ty * 4) = ev;
    }
}

__global__ __launch_bounds__(256) void tanh_reduce_kernel(
    const ushort* __restrict__ ws16, const float* __restrict__ agg,
    float* __restrict__ partial)
{
    __shared__ __align__(16) float et [64][68];   // [a][n] = E1d*E2d (fp32)
    __shared__ __align__(16) float ect[64][68];   // [a][m] = E1c*E2c
    __shared__ float aggs[128];                   // 2*agg for this half

    const int t    = threadIdx.x;
    const int m0   = blockIdx.x * 64;
    const int n0   = blockIdx.y * 64;
    const int b    = blockIdx.z >> 1;
    const int half = blockIdx.z & 1;              // a-half (128 a's per block)

    const size_t PLANE = (size_t)A_DIM * NROWS;
    const ushort* E1d = ws16;
    const ushort* E2d = ws16 + PLANE;
    const ushort* E1c = ws16 + 2 * PLANE;
    const ushort* E2c = ws16 + 3 * PLANE;
    const int row_n = b * 512 + n0;
    const int row_m = b * 512 + m0;

    const int tx = t & 15;                   // m group (4 m's)
    const int ty = t >> 4;                   // n group (4 n's)

    if (t < 128) aggs[t] = 2.0f * agg[half * 128 + t];

    float acc[4][4];
#pragma unroll
    for (int i = 0; i < 4; i++)
#pragma unroll
        for (int j = 0; j < 4; j++) acc[i][j] = 0.f;
    float sagg = 0.f;

    const int aL = t >> 2;                   // staging row 0..63
    const int qd = t & 3;                    // staging quarter

    for (int ch = 0; ch < 2; ch++) {
        const int a0 = half * 128 + ch * 64;
        __syncthreads();                     // prev chunk's LDS reads done (+aggs on ch0)
#pragma unroll
        for (int r = 0; r < 4; r++) {
            const int seg = qd * 16 + r * 4;
            const size_t offn = (size_t)(a0 + aL) * NROWS + row_n + seg;
            const size_t offm = (size_t)(a0 + aL) * NROWS + row_m + seg;
            us4 d1 = *(const us4*)(E1d + offn);
            us4 d2 = *(const us4*)(E2d + offn);
            us4 c1 = *(const us4*)(E1c + offm);
            us4 c2 = *(const us4*)(E2c + offm);
            float4 ev, cv;
            ev.x = bf2f(d1[0]) * bf2f(d2[0]); ev.y = bf2f(d1[1]) * bf2f(d2[1]);
            ev.z = bf2f(d1[2]) * bf2f(d2[2]); ev.w = bf2f(d1[3]) * bf2f(d2[3]);
            cv.x = bf2f(c1[0]) * bf2f(c2[0]); cv.y = bf2f(c1[1]) * bf2f(c2[1]);
            cv.z = bf2f(c1[2]) * bf2f(c2[2]); cv.w = bf2f(c1[3]) * bf2f(c2[3]);
            *(float4*)&et [aL][seg] = ev;
            *(float4*)&ect[aL][seg] = cv;
        }
        __syncthreads();

        for (int p = 0; p < 32; p++) {       // a-pairs: one rcp per 2 a-terms
            const float2 ag = *(const float2*)&aggs[ch * 64 + p * 2];
            sagg += ag.x + ag.y;
            float4 e0 = *(const float4*)&et [p * 2 + 0][ty * 4];   // 4 n's, a0
            float4 e1 = *(const float4*)&et [p * 2 + 1][ty * 4];   // 4 n's, a1
            float4 f0 = *(const float4*)&ect[p * 2 + 0][tx * 4];   // 4 m's, a0
            float4 f1 = *(const float4*)&ect[p * 2 + 1][tx * 4];   // 4 m's, a1
            const float ea0[4] = {e0.x, e0.y, e0.z, e0.w};
            const float ea1[4] = {e1.x, e1.y, e1.z, e1.w};
            const float fa0[4] = {f0.x, f0.y, f0.z, f0.w};
            const float fa1[4] = {f1.x, f1.y, f1.z, f1.w};
#pragma unroll
            for (int i = 0; i < 4; i++)
#pragma unroll
                for (int j = 0; j < 4; j++) {
                    float q0 = fmaf(ea0[i], fa0[j], 1.f);
                    float q1 = fmaf(ea1[i], fa1[j], 1.f);
                    acc[i][j] = fmaf(fmaf(ag.x, q1, ag.y * q0),
                                     __builtin_amdgcn_rcpf(q0 * q1), acc[i][j]);
                }
        }
    }

    // partial = sum_{a in half} agg[a] - sum 2agg/q   (tanh = 1 - 2/q)
    const float base = 0.5f * sagg;
    float* pl = partial + (size_t)half * (1 << 20);   // 1,048,576 floats per plane
#pragma unroll
    for (int i = 0; i < 4; i++) {
        float4 v;
        v.x = base - acc[i][0]; v.y = base - acc[i][1];
        v.z = base - acc[i][2]; v.w = base - acc[i][3];
        *(float4*)(pl + ((size_t)(b * 512 + n0 + ty * 4 + i) * 512) + m0 + tx * 4) = v;
    }
}

__global__ __launch_bounds__(256) void combine_kernel(
    const float* __restrict__ partial, float* __restrict__ out)
{
    const int idx = blockIdx.x * 256 + threadIdx.x;   // 131072 threads
    const float4* p0 = (const float4*)partial;
    const float4* p1 = (const float4*)(partial + (1 << 20));
    float4* o = (float4*)out;
#pragma unroll
    for (int r = 0; r < 2; r++) {                     // 262144 float4 total
        const int i = idx + r * 131072;
        float4 a = p0[i], b = p1[i], v;
        v.x = a.x + b.x; v.y = a.y + b.y; v.z = a.z + b.z; v.w = a.w + b.w;
        o[i] = v;
    }
}

extern "C" void kernel_launch(void* const* d_in, const int* in_sizes, int n_in,
                              void* d_out, int out_size, void* d_ws, size_t ws_size,
                              hipStream_t stream) {
    const float* data = (const float*)d_in[0];
    const float* crit = (const float*)d_in[1];
    const float* Wl   = (const float*)d_in[2];
    const float* bl   = (const float*)d_in[3];
    const float* Wr   = (const float*)d_in[4];
    const float* br   = (const float*)d_in[5];
    const float* agg  = (const float*)d_in[6];
    float* out   = (float*)d_out;
    ushort* ws16 = (ushort*)d_ws;                 // 4 bf16 factor planes = 4 MB
    float* wspart = (float*)((char*)d_ws + 4u * 1024u * 1024u);  // 2 fp32 partial planes

    // Phase 1: 32 row-tiles x 4 col-tiles x 2 K-halves x 2 sources = 512 blocks
    proj_exp_kernel<<<dim3(512), 256, 0, stream>>>(data, crit, Wl, bl, Wr, br, ws16);

    // Phase 2: (8 m-tiles x 8 n-tiles) x (4 b x 2 a-halves) = 512 blocks, 64x64 tiles
    tanh_reduce_kernel<<<dim3(8, 8, 8), 256, 0, stream>>>(ws16, agg, wspart);

    // Phase 3: out = p0 + p1
    combine_kernel<<<dim3(512), 256, 0, stream>>>(wspart, out);
}

// Round 7
// 112.980 us; speedup vs baseline: 1.0518x; 1.0518x over previous
//
#include <hip/hip_runtime.h>

// ForwardDistance: out[b,n,m] = sum_a agg[a] * tanh(datalin[b,n,a] + critlin[b,m,a])
// tanh(x+y) = 1 - 2/(1 + e^{2x} e^{2y})
// R7: projections moved to MFMA (bf16). R6 post-mortem: fp32 VALU GEMM was
//   LDS-ISSUE-bound (512 ds_read_b128/wave ~ 20 us). MFMA needs 2 b128 per 8192
//   MACs. A-frags straight from global (fp32->bf16 RNE pack, no barriers);
//   W pre-transposed once to bf16 Wt[a][k] so B-frags are b128 LDS reads.
//   Single Ed/Ec bf16 planes (K-split factors removed).
// Phase 2 (tanh_reduce): R6 structure, 64x64 tile, 4x4/thread, a-halves, pair-
//   grouped rcp; staging now reads 2 planes (no factor multiply). Phase 3 combine.

#define A_DIM 256
#define K_DIM 512
#define NROWS 2048   // rows per source (B*N == B*M)

typedef unsigned short ushort;
typedef __attribute__((ext_vector_type(4))) unsigned short us4;
typedef __attribute__((ext_vector_type(8))) unsigned short us8;
typedef __attribute__((ext_vector_type(8))) short short8;   // bf16x8 MFMA frag
typedef __attribute__((ext_vector_type(4))) float f32x4;    // MFMA acc

__device__ inline ushort f2bf(float x) {    // round-to-nearest-even bf16
    union { float f; unsigned u; } v; v.f = x;
    unsigned r = v.u + 0x7FFFu + ((v.u >> 16) & 1u);
    return (ushort)(r >> 16);
}
__device__ inline float bf2f(ushort h) {
    union { unsigned u; float f; } v; v.u = ((unsigned)h) << 16; return v.f;
}
__device__ inline unsigned pack2bf(float lo, float hi) {
    return (unsigned)f2bf(lo) | ((unsigned)f2bf(hi) << 16);
}

// ---- W[k][a] fp32 -> Wt[a][k] bf16, once ----
__global__ __launch_bounds__(256) void transpose_w_kernel(
    const float* __restrict__ Wl, const float* __restrict__ Wr,
    ushort* __restrict__ wt)
{
    __shared__ float tile[64][68];
    const int t   = threadIdx.x;
    const int bid = blockIdx.x;
    const int at  = bid & 3;          // a tile
    const int kt  = (bid >> 2) & 7;   // k tile
    const int src = bid >> 5;
    const int a0 = at * 64, k0 = kt * 64;
    const float* W = src ? Wr : Wl;
    ushort* out = wt + (size_t)src * (A_DIM * K_DIM);

    const int c4 = (t & 15) * 4;
    const int kr = t >> 4;
#pragma unroll
    for (int r = 0; r < 4; r++) {
        const int k = kr + r * 16;
        *(float4*)&tile[k][c4] = *(const float4*)(W + (size_t)(k0 + k) * A_DIM + a0 + c4);
    }
    __syncthreads();
    const int aL  = t & 63;           // lane -> consecutive dwords: conflict-free
    const int ks0 = (t >> 6) * 16;
#pragma unroll
    for (int g = 0; g < 4; g++) {
        us4 o;
#pragma unroll
        for (int i = 0; i < 4; i++) o[i] = f2bf(tile[ks0 + g * 4 + i][aL]);
        *(us4*)(out + (size_t)(a0 + aL) * K_DIM + k0 + ks0 + g * 4) = o;
    }
}

// ---- bf16 MFMA GEMM + exp2 epilogue -> Ed/Ec bf16 planes [a][row] ----
__global__ __launch_bounds__(256) void proj_mfma_kernel(
    const float* __restrict__ data, const float* __restrict__ crit,
    const float* __restrict__ bl, const float* __restrict__ br,
    const ushort* __restrict__ wt, ushort* __restrict__ eplanes)
{
    __shared__ ushort Ws[64][264];   // [a][k-chunk 256], pad 264: 4-bank rotate/row

    const int t   = threadIdx.x;
    const int bid = blockIdx.x;
    const int ct  = bid & 3;         // a-col tile (64)
    const int rt  = bid >> 2;        // 0..127 row tile (32 rows)
    const int src = rt >> 6;
    const int lr0 = (rt & 63) * 32;
    const int c0  = ct * 64;

    const float* X    = src ? crit : data;
    const float* bias = src ? br : bl;
    const ushort* Wt  = wt + (size_t)src * (A_DIM * K_DIM);
    ushort* E = eplanes + (size_t)src * ((size_t)A_DIM * NROWS);

    const int lane = t & 63;
    const int wid  = t >> 6;             // 4 waves: 2 (rows) x 2 (cols)
    const int wm   = wid >> 1, wn = wid & 1;
    const int quad = lane >> 4, l16 = lane & 15;

    // A: this lane's X row, k = s*32 + quad*8 + j
    const float* xrow = X + (size_t)(lr0 + wm * 16 + l16) * K_DIM + quad * 8;
    const int aloc0 = wn * 32 + l16;     // B tiles at aloc0 and aloc0+16

    f32x4 acc0 = {0.f, 0.f, 0.f, 0.f}, acc1 = {0.f, 0.f, 0.f, 0.f};

    float4 pa = *(const float4*)(xrow);
    float4 pb = *(const float4*)(xrow + 4);

    for (int kc = 0; kc < 2; kc++) {     // two 256-k LDS chunks of W
        __syncthreads();                 // prev chunk's frag reads done
        {   // stage Ws[a][0..255] from Wt[c0+a][kc*256 ..]: 8 x us8 per thread
            const int a  = t & 63;
            const int ks = (t >> 6) * 64;
            const ushort* s = Wt + (size_t)(c0 + a) * K_DIM + kc * 256 + ks;
#pragma unroll
            for (int i = 0; i < 8; i++)
                *(us8*)&Ws[a][ks + i * 8] = *(const us8*)(s + i * 8);
        }
        __syncthreads();

#pragma unroll
        for (int ls = 0; ls < 8; ls++) {
            const int s = kc * 8 + ls;
            float4 ca = pa, cb = pb;
            if (s < 15) {                // rolling A prefetch
                pa = *(const float4*)(xrow + (s + 1) * 32);
                pb = *(const float4*)(xrow + (s + 1) * 32 + 4);
            }
            union { short8 s8; unsigned u[4]; } af;
            af.u[0] = pack2bf(ca.x, ca.y);
            af.u[1] = pack2bf(ca.z, ca.w);
            af.u[2] = pack2bf(cb.x, cb.y);
            af.u[3] = pack2bf(cb.z, cb.w);
            short8 b0 = *(const short8*)&Ws[aloc0     ][ls * 32 + quad * 8];
            short8 b1 = *(const short8*)&Ws[aloc0 + 16][ls * 32 + quad * 8];
            acc0 = __builtin_amdgcn_mfma_f32_16x16x32_bf16(af.s8, b0, acc0, 0, 0, 0);
            acc1 = __builtin_amdgcn_mfma_f32_16x16x32_bf16(af.s8, b1, acc1, 0, 0, 0);
        }
    }

    // epilogue: C/D layout col=lane&15 (a), row=quad*4+reg. E = exp2(clamp(c2*(x+b)))
    const float c2 = 2.8853900817779268f;    // 2*log2(e)
    const int a_col0 = c0 + wn * 32 + l16;
    const int a_col1 = a_col0 + 16;
    const int row0   = lr0 + wm * 16 + quad * 4;
    const float bv0 = bias[a_col0], bv1 = bias[a_col1];
    us4 e0, e1;
#pragma unroll
    for (int i = 0; i < 4; i++) {
        float v0 = (acc0[i] + bv0) * c2;
        float v1 = (acc1[i] + bv1) * c2;
        v0 = fminf(fmaxf(v0, -15.f), 15.f);   // bounds q<=1+2^30 for rcp path
        v1 = fminf(fmaxf(v1, -15.f), 15.f);
        e0[i] = f2bf(__builtin_amdgcn_exp2f(v0));
        e1[i] = f2bf(__builtin_amdgcn_exp2f(v1));
    }
    *(us4*)(E + (size_t)a_col0 * NROWS + row0) = e0;
    *(us4*)(E + (size_t)a_col1 * NROWS + row0) = e1;
}

// ---- tanh-reduce: 64x64 tile, 4x4/thread, a-halves, pair-grouped rcp ----
__global__ __launch_bounds__(256) void tanh_reduce_kernel(
    const ushort* __restrict__ eplanes, const float* __restrict__ agg,
    float* __restrict__ partial)
{
    __shared__ __align__(16) float et [64][68];   // [a][n]
    __shared__ __align__(16) float ect[64][68];   // [a][m]
    __shared__ float aggs[128];

    const int t    = threadIdx.x;
    const int m0   = blockIdx.x * 64;
    const int n0   = blockIdx.y * 64;
    const int b    = blockIdx.z >> 1;
    const int half = blockIdx.z & 1;

    const size_t PLANE = (size_t)A_DIM * NROWS;
    const ushort* Ed = eplanes;
    const ushort* Ec = eplanes + PLANE;
    const int row_n = b * 512 + n0;
    const int row_m = b * 512 + m0;

    const int tx = t & 15;
    const int ty = t >> 4;

    if (t < 128) aggs[t] = 2.0f * agg[half * 128 + t];

    float acc[4][4];
#pragma unroll
    for (int i = 0; i < 4; i++)
#pragma unroll
        for (int j = 0; j < 4; j++) acc[i][j] = 0.f;
    float sagg = 0.f;

    const int aL = t >> 2;
    const int qd = t & 3;

    for (int ch = 0; ch < 2; ch++) {
        const int a0 = half * 128 + ch * 64;
        __syncthreads();
#pragma unroll
        for (int r = 0; r < 4; r++) {
            const int seg = qd * 16 + r * 4;
            us4 d = *(const us4*)(Ed + (size_t)(a0 + aL) * NROWS + row_n + seg);
            us4 c = *(const us4*)(Ec + (size_t)(a0 + aL) * NROWS + row_m + seg);
            float4 ev, cv;
            ev.x = bf2f(d[0]); ev.y = bf2f(d[1]); ev.z = bf2f(d[2]); ev.w = bf2f(d[3]);
            cv.x = bf2f(c[0]); cv.y = bf2f(c[1]); cv.z = bf2f(c[2]); cv.w = bf2f(c[3]);
            *(float4*)&et [aL][seg] = ev;
            *(float4*)&ect[aL][seg] = cv;
        }
        __syncthreads();

        for (int p = 0; p < 32; p++) {       // one rcp per 2 a-terms
            const float2 ag = *(const float2*)&aggs[ch * 64 + p * 2];
            sagg += ag.x + ag.y;
            float4 e0 = *(const float4*)&et [p * 2 + 0][ty * 4];
            float4 e1 = *(const float4*)&et [p * 2 + 1][ty * 4];
            float4 f0 = *(const float4*)&ect[p * 2 + 0][tx * 4];
            float4 f1 = *(const float4*)&ect[p * 2 + 1][tx * 4];
            const float ea0[4] = {e0.x, e0.y, e0.z, e0.w};
            const float ea1[4] = {e1.x, e1.y, e1.z, e1.w};
            const float fa0[4] = {f0.x, f0.y, f0.z, f0.w};
            const float fa1[4] = {f1.x, f1.y, f1.z, f1.w};
#pragma unroll
            for (int i = 0; i < 4; i++)
#pragma unroll
                for (int j = 0; j < 4; j++) {
                    float q0 = fmaf(ea0[i], fa0[j], 1.f);
                    float q1 = fmaf(ea1[i], fa1[j], 1.f);
                    acc[i][j] = fmaf(fmaf(ag.x, q1, ag.y * q0),
                                     __builtin_amdgcn_rcpf(q0 * q1), acc[i][j]);
                }
        }
    }

    const float base = 0.5f * sagg;
    float* pl = partial + (size_t)half * (1 << 20);
#pragma unroll
    for (int i = 0; i < 4; i++) {
        float4 v;
        v.x = base - acc[i][0]; v.y = base - acc[i][1];
        v.z = base - acc[i][2]; v.w = base - acc[i][3];
        *(float4*)(pl + ((size_t)(b * 512 + n0 + ty * 4 + i) * 512) + m0 + tx * 4) = v;
    }
}

__global__ __launch_bounds__(256) void combine_kernel(
    const float* __restrict__ partial, float* __restrict__ out)
{
    const int idx = blockIdx.x * 256 + threadIdx.x;
    const float4* p0 = (const float4*)partial;
    const float4* p1 = (const float4*)(partial + (1 << 20));
    float4* o = (float4*)out;
#pragma unroll
    for (int r = 0; r < 2; r++) {
        const int i = idx + r * 131072;
        float4 a = p0[i], b = p1[i], v;
        v.x = a.x + b.x; v.y = a.y + b.y; v.z = a.z + b.z; v.w = a.w + b.w;
        o[i] = v;
    }
}

extern "C" void kernel_launch(void* const* d_in, const int* in_sizes, int n_in,
                              void* d_out, int out_size, void* d_ws, size_t ws_size,
                              hipStream_t stream) {
    const float* data = (const float*)d_in[0];
    const float* crit = (const float*)d_in[1];
    const float* Wl   = (const float*)d_in[2];
    const float* bl   = (const float*)d_in[3];
    const float* Wr   = (const float*)d_in[4];
    const float* br   = (const float*)d_in[5];
    const float* agg  = (const float*)d_in[6];
    float* out = (float*)d_out;

    ushort* ws16 = (ushort*)d_ws;
    // layout: Ed [256][2048] bf16 (1 MB) | Ec (1 MB) | Wt 2x[256][512] bf16 (1 MB)
    ushort* eplanes = ws16;
    ushort* wt      = ws16 + 2 * (size_t)A_DIM * NROWS;
    float* wspart   = (float*)((char*)d_ws + 8u * 1024u * 1024u);  // 2 partial planes

    // W transpose+cast: 8 k-tiles x 4 a-tiles x 2 src = 64 blocks
    transpose_w_kernel<<<dim3(64), 256, 0, stream>>>(Wl, Wr, wt);

    // proj: 128 row-tiles(32) x 4 col-tiles(64) = 512 blocks
    proj_mfma_kernel<<<dim3(512), 256, 0, stream>>>(data, crit, bl, br, wt, eplanes);

    // tanh: (8 m x 8 n) x (4 b x 2 a-halves) = 512 blocks
    tanh_reduce_kernel<<<dim3(8, 8, 8), 256, 0, stream>>>(eplanes, agg, wspart);

    combine_kernel<<<dim3(512), 256, 0, stream>>>(wspart, out);
}

// Round 8
// 110.309 us; speedup vs baseline: 1.0773x; 1.0242x over previous
//
#include <hip/hip_runtime.h>

// ForwardDistance: out[b,n,m] = sum_a agg[a] * tanh(datalin[b,n,a] + critlin[b,m,a])
// tanh(x+y) = 1 - 2/(1 + e^{2x} e^{2y})
// R8: combine kernel + partial planes eliminated. tanh_reduce now 512-thread
//   blocks: a=256 split across the block's two wave-halves (128 a each) for one
//   64x64 out tile; LDS exchange (stride-17, conflict-free) merges halves and
//   writes out directly. LDS 69 KB -> 2 blocks/CU = 4 waves/SIMD (was 2).
//   proj (MFMA bf16, R7) and transpose_w unchanged.

#define A_DIM 256
#define K_DIM 512
#define NROWS 2048   // rows per source (B*N == B*M)

typedef unsigned short ushort;
typedef __attribute__((ext_vector_type(4))) unsigned short us4;
typedef __attribute__((ext_vector_type(8))) unsigned short us8;
typedef __attribute__((ext_vector_type(8))) short short8;   // bf16x8 MFMA frag
typedef __attribute__((ext_vector_type(4))) float f32x4;    // MFMA acc

__device__ inline ushort f2bf(float x) {    // round-to-nearest-even bf16
    union { float f; unsigned u; } v; v.f = x;
    unsigned r = v.u + 0x7FFFu + ((v.u >> 16) & 1u);
    return (ushort)(r >> 16);
}
__device__ inline float bf2f(ushort h) {
    union { unsigned u; float f; } v; v.u = ((unsigned)h) << 16; return v.f;
}
__device__ inline unsigned pack2bf(float lo, float hi) {
    return (unsigned)f2bf(lo) | ((unsigned)f2bf(hi) << 16);
}

// ---- W[k][a] fp32 -> Wt[a][k] bf16, once ----
__global__ __launch_bounds__(256) void transpose_w_kernel(
    const float* __restrict__ Wl, const float* __restrict__ Wr,
    ushort* __restrict__ wt)
{
    __shared__ float tile[64][68];
    const int t   = threadIdx.x;
    const int bid = blockIdx.x;
    const int at  = bid & 3;          // a tile
    const int kt  = (bid >> 2) & 7;   // k tile
    const int src = bid >> 5;
    const int a0 = at * 64, k0 = kt * 64;
    const float* W = src ? Wr : Wl;
    ushort* out = wt + (size_t)src * (A_DIM * K_DIM);

    const int c4 = (t & 15) * 4;
    const int kr = t >> 4;
#pragma unroll
    for (int r = 0; r < 4; r++) {
        const int k = kr + r * 16;
        *(float4*)&tile[k][c4] = *(const float4*)(W + (size_t)(k0 + k) * A_DIM + a0 + c4);
    }
    __syncthreads();
    const int aL  = t & 63;           // lane -> consecutive dwords: conflict-free
    const int ks0 = (t >> 6) * 16;
#pragma unroll
    for (int g = 0; g < 4; g++) {
        us4 o;
#pragma unroll
        for (int i = 0; i < 4; i++) o[i] = f2bf(tile[ks0 + g * 4 + i][aL]);
        *(us4*)(out + (size_t)(a0 + aL) * K_DIM + k0 + ks0 + g * 4) = o;
    }
}

// ---- bf16 MFMA GEMM + exp2 epilogue -> Ed/Ec bf16 planes [a][row] ----
__global__ __launch_bounds__(256) void proj_mfma_kernel(
    const float* __restrict__ data, const float* __restrict__ crit,
    const float* __restrict__ bl, const float* __restrict__ br,
    const ushort* __restrict__ wt, ushort* __restrict__ eplanes)
{
    __shared__ ushort Ws[64][264];   // [a][k-chunk 256], pad 264

    const int t   = threadIdx.x;
    const int bid = blockIdx.x;
    const int ct  = bid & 3;         // a-col tile (64)
    const int rt  = bid >> 2;        // 0..127 row tile (32 rows)
    const int src = rt >> 6;
    const int lr0 = (rt & 63) * 32;
    const int c0  = ct * 64;

    const float* X    = src ? crit : data;
    const float* bias = src ? br : bl;
    const ushort* Wt  = wt + (size_t)src * (A_DIM * K_DIM);
    ushort* E = eplanes + (size_t)src * ((size_t)A_DIM * NROWS);

    const int lane = t & 63;
    const int wid  = t >> 6;             // 4 waves: 2 (rows) x 2 (cols)
    const int wm   = wid >> 1, wn = wid & 1;
    const int quad = lane >> 4, l16 = lane & 15;

    const float* xrow = X + (size_t)(lr0 + wm * 16 + l16) * K_DIM + quad * 8;
    const int aloc0 = wn * 32 + l16;

    f32x4 acc0 = {0.f, 0.f, 0.f, 0.f}, acc1 = {0.f, 0.f, 0.f, 0.f};

    float4 pa = *(const float4*)(xrow);
    float4 pb = *(const float4*)(xrow + 4);

    for (int kc = 0; kc < 2; kc++) {     // two 256-k LDS chunks of W
        __syncthreads();
        {   // stage Ws[a][0..255] from Wt[c0+a][kc*256 ..]
            const int a  = t & 63;
            const int ks = (t >> 6) * 64;
            const ushort* s = Wt + (size_t)(c0 + a) * K_DIM + kc * 256 + ks;
#pragma unroll
            for (int i = 0; i < 8; i++)
                *(us8*)&Ws[a][ks + i * 8] = *(const us8*)(s + i * 8);
        }
        __syncthreads();

#pragma unroll
        for (int ls = 0; ls < 8; ls++) {
            const int s = kc * 8 + ls;
            float4 ca = pa, cb = pb;
            if (s < 15) {                // rolling A prefetch
                pa = *(const float4*)(xrow + (s + 1) * 32);
                pb = *(const float4*)(xrow + (s + 1) * 32 + 4);
            }
            union { short8 s8; unsigned u[4]; } af;
            af.u[0] = pack2bf(ca.x, ca.y);
            af.u[1] = pack2bf(ca.z, ca.w);
            af.u[2] = pack2bf(cb.x, cb.y);
            af.u[3] = pack2bf(cb.z, cb.w);
            short8 b0 = *(const short8*)&Ws[aloc0     ][ls * 32 + quad * 8];
            short8 b1 = *(const short8*)&Ws[aloc0 + 16][ls * 32 + quad * 8];
            acc0 = __builtin_amdgcn_mfma_f32_16x16x32_bf16(af.s8, b0, acc0, 0, 0, 0);
            acc1 = __builtin_amdgcn_mfma_f32_16x16x32_bf16(af.s8, b1, acc1, 0, 0, 0);
        }
    }

    // epilogue: C/D layout col=lane&15 (a), row=quad*4+reg
    const float c2 = 2.8853900817779268f;    // 2*log2(e)
    const int a_col0 = c0 + wn * 32 + l16;
    const int a_col1 = a_col0 + 16;
    const int row0   = lr0 + wm * 16 + quad * 4;
    const float bv0 = bias[a_col0], bv1 = bias[a_col1];
    us4 e0, e1;
#pragma unroll
    for (int i = 0; i < 4; i++) {
        float v0 = (acc0[i] + bv0) * c2;
        float v1 = (acc1[i] + bv1) * c2;
        v0 = fminf(fmaxf(v0, -15.f), 15.f);   // bounds q<=1+2^30 for rcp path
        v1 = fminf(fmaxf(v1, -15.f), 15.f);
        e0[i] = f2bf(__builtin_amdgcn_exp2f(v0));
        e1[i] = f2bf(__builtin_amdgcn_exp2f(v1));
    }
    *(us4*)(E + (size_t)a_col0 * NROWS + row0) = e0;
    *(us4*)(E + (size_t)a_col1 * NROWS + row0) = e1;
}

// ---- tanh-reduce: 512 threads, 64x64 tile, a-halves across wave-halves ----
__global__ __launch_bounds__(512) void tanh_reduce_kernel(
    const ushort* __restrict__ eplanes, const float* __restrict__ agg,
    float* __restrict__ out)
{
    __shared__ __align__(16) float et [2][64][68];   // [half][a][n]
    __shared__ __align__(16) float ect[2][64][68];   // [half][a][m]
    __shared__ float aggs[256];

    const int t  = threadIdx.x;
    const int h  = t >> 8;               // a-half (0: a<128, 1: a>=128)
    const int u  = t & 255;              // thread id within half
    const int m0 = blockIdx.x * 64;
    const int n0 = blockIdx.y * 64;
    const int b  = blockIdx.z;

    const size_t PLANE = (size_t)A_DIM * NROWS;
    const ushort* Ed = eplanes;
    const ushort* Ec = eplanes + PLANE;
    const int row_n = b * 512 + n0;
    const int row_m = b * 512 + m0;

    const int tx = u & 15;               // m group (4 m's)
    const int ty = u >> 4;               // n group (4 n's)

    if (t < 256) aggs[t] = 2.0f * agg[t];

    float acc[4][4];
#pragma unroll
    for (int i = 0; i < 4; i++)
#pragma unroll
        for (int j = 0; j < 4; j++) acc[i][j] = 0.f;
    float sagg = 0.f;

    const int aL = u >> 2;               // staging row 0..63
    const int qd = u & 3;                // staging quarter

    float (*eth)[68]  = et[h];
    float (*ecth)[68] = ect[h];

    for (int ch = 0; ch < 2; ch++) {
        const int a0 = h * 128 + ch * 64;
        __syncthreads();                 // prev chunk's LDS reads done (+aggs on ch0)
#pragma unroll
        for (int r = 0; r < 4; r++) {
            const int seg = qd * 16 + r * 4;
            us4 d = *(const us4*)(Ed + (size_t)(a0 + aL) * NROWS + row_n + seg);
            us4 c = *(const us4*)(Ec + (size_t)(a0 + aL) * NROWS + row_m + seg);
            float4 ev, cv;
            ev.x = bf2f(d[0]); ev.y = bf2f(d[1]); ev.z = bf2f(d[2]); ev.w = bf2f(d[3]);
            cv.x = bf2f(c[0]); cv.y = bf2f(c[1]); cv.z = bf2f(c[2]); cv.w = bf2f(c[3]);
            *(float4*)&eth [aL][seg] = ev;
            *(float4*)&ecth[aL][seg] = cv;
        }
        __syncthreads();

        for (int p = 0; p < 32; p++) {   // pair-grouped: one rcp per 2 a-terms
            const float2 ag = *(const float2*)&aggs[h * 128 + ch * 64 + p * 2];
            sagg += ag.x + ag.y;
            float4 e0 = *(const float4*)&eth [p * 2 + 0][ty * 4];
            float4 e1 = *(const float4*)&eth [p * 2 + 1][ty * 4];
            float4 f0 = *(const float4*)&ecth[p * 2 + 0][tx * 4];
            float4 f1 = *(const float4*)&ecth[p * 2 + 1][tx * 4];
            const float ea0[4] = {e0.x, e0.y, e0.z, e0.w};
            const float ea1[4] = {e1.x, e1.y, e1.z, e1.w};
            const float fa0[4] = {f0.x, f0.y, f0.z, f0.w};
            const float fa1[4] = {f1.x, f1.y, f1.z, f1.w};
#pragma unroll
            for (int i = 0; i < 4; i++)
#pragma unroll
                for (int j = 0; j < 4; j++) {
                    float q0 = fmaf(ea0[i], fa0[j], 1.f);
                    float q1 = fmaf(ea1[i], fa1[j], 1.f);
                    acc[i][j] = fmaf(fmaf(ag.x, q1, ag.y * q0),
                                     __builtin_amdgcn_rcpf(q0 * q1), acc[i][j]);
                }
        }
    }

    // partial_h = 0.5*sagg - acc ; merge halves via LDS (stride 17: conflict-free)
    const float base = 0.5f * sagg;
    float* xb = (float*)ect;             // reuse (>= 17 KB available)
    __syncthreads();                     // all LDS reads of et/ect complete
    if (h == 1) {
#pragma unroll
        for (int i = 0; i < 4; i++)
#pragma unroll
            for (int j = 0; j < 4; j++)
                xb[u * 17 + i * 4 + j] = base - acc[i][j];
    }
    __syncthreads();
    if (h == 0) {
#pragma unroll
        for (int i = 0; i < 4; i++) {
            float4 v;
            v.x = (base - acc[i][0]) + xb[u * 17 + i * 4 + 0];
            v.y = (base - acc[i][1]) + xb[u * 17 + i * 4 + 1];
            v.z = (base - acc[i][2]) + xb[u * 17 + i * 4 + 2];
            v.w = (base - acc[i][3]) + xb[u * 17 + i * 4 + 3];
            *(float4*)(out + ((size_t)(b * 512 + n0 + ty * 4 + i) * 512) + m0 + tx * 4) = v;
        }
    }
}

extern "C" void kernel_launch(void* const* d_in, const int* in_sizes, int n_in,
                              void* d_out, int out_size, void* d_ws, size_t ws_size,
                              hipStream_t stream) {
    const float* data = (const float*)d_in[0];
    const float* crit = (const float*)d_in[1];
    const float* Wl   = (const float*)d_in[2];
    const float* bl   = (const float*)d_in[3];
    const float* Wr   = (const float*)d_in[4];
    const float* br   = (const float*)d_in[5];
    const float* agg  = (const float*)d_in[6];
    float* out = (float*)d_out;

    ushort* ws16 = (ushort*)d_ws;
    // layout: Ed [256][2048] bf16 (1 MB) | Ec (1 MB) | Wt 2x[256][512] bf16 (1 MB)
    ushort* eplanes = ws16;
    ushort* wt      = ws16 + 2 * (size_t)A_DIM * NROWS;

    // W transpose+cast: 8 k-tiles x 4 a-tiles x 2 src = 64 blocks
    transpose_w_kernel<<<dim3(64), 256, 0, stream>>>(Wl, Wr, wt);

    // proj: 128 row-tiles(32) x 4 col-tiles(64) = 512 blocks
    proj_mfma_kernel<<<dim3(512), 256, 0, stream>>>(data, crit, bl, br, wt, eplanes);

    // tanh: (8 m x 8 n) x 4 b = 256 blocks x 512 threads; writes out directly
    tanh_reduce_kernel<<<dim3(8, 8, 4), 512, 0, stream>>>(eplanes, agg, out);
}